// Round 1
// baseline (831.323 us; speedup 1.0000x reference)
//
#include <hip/hip_runtime.h>
#include <math.h>

// BoundaryFocalLoss: B=128, T=200000, f32 inputs, i32 targets, f32 mask -> scalar f32.
// Memory-bound: 12 B/elem * 25.6M = ~307 MB read. Roofline @6.3 TB/s ~= 49 us.

#define B_DIM 128
#define T_DIM 200000

constexpr int GROUPS_PER_ROW = T_DIM / 4;           // 50000 float4-groups per row
constexpr int BLOCK = 256;
constexpr int BLOCKS_PER_ROW = (GROUPS_PER_ROW + BLOCK - 1) / BLOCK;  // 196

__global__ __launch_bounds__(BLOCK) void bfl_main(
    const float* __restrict__ inputs,
    const int*   __restrict__ targets,
    const float* __restrict__ mask,
    float*       __restrict__ sums)   // sums[0] = loss sum, sums[1] = mask sum
{
    const int b     = blockIdx.y;
    const int g_row = blockIdx.x * BLOCK + threadIdx.x;

    float lsum = 0.0f, msum = 0.0f;

    if (g_row < GROUPS_PER_ROW) {
        const long long row = (long long)b * T_DIM;
        const int t0 = g_row * 4;

        const float4 x4 = ((const float4*)(inputs + row))[g_row];
        const float4 m4 = ((const float4*)(mask   + row))[g_row];
        const int4 curr = ((const int4*)(targets + row))[g_row];
        const int4 prev = (g_row > 0)
            ? ((const int4*)(targets + row))[g_row - 1]
            : make_int4(curr.x, curr.x, curr.x, curr.x);
        const int4 next = (g_row < GROUPS_PER_ROW - 1)
            ? ((const int4*)(targets + row))[g_row + 1]
            : make_int4(curr.w, curr.w, curr.w, curr.w);

        // tg[k] = targets[t0 - 4 + k], k = 0..10  (halo -4..+6)
        int tg[11] = {prev.x, prev.y, prev.z, prev.w,
                      curr.x, curr.y, curr.z, curr.w,
                      next.x, next.y, next.z};

        // trans bit k <-> j = t0 - 4 + k; trans[j] valid for 1 <= j <= T-1
        unsigned mbits = 0u;
        #pragma unroll
        for (int k = 1; k <= 10; ++k) {
            const int j = t0 - 4 + k;
            const bool valid = (j >= 1) && (j < T_DIM);
            if (valid && (tg[k] != tg[k - 1])) mbits |= (1u << k);
        }

        const float xs[4] = {x4.x, x4.y, x4.z, x4.w};
        const float ms[4] = {m4.x, m4.y, m4.z, m4.w};
        const int   ts[4] = {curr.x, curr.y, curr.z, curr.w};

        #pragma unroll
        for (int ii = 0; ii < 4; ++ii) {
            const float x  = xs[ii];
            const float mm = ms[ii];
            const bool pos = ((float)ts[ii]) > 0.5f;

            const float smoothed = pos ? 0.975f : 0.025f;   // pos*(1-ls) + ls/2
            // boundary[i] = OR of trans bits (ii+1 .. ii+7)  <-> j in [i-3, i+3]
            const float w = ((mbits >> (ii + 1)) & 0x7Fu) ? 5.0f : 1.0f;

            const float p        = 1.0f / (1.0f + __expf(-x));
            const float adaptive = 1.0f - fabsf(p - 0.5f);  // 1 - |p-0.5|*2*0.5

            const float bce = fmaxf(x, 0.0f) - x * smoothed + log1pf(__expf(-fabsf(x)));
            const float pt  = __expf(-bce);
            const float alpha_w = pos ? 0.25f : 0.75f;
            const float om = 1.0f - pt;

            lsum += alpha_w * om * om * bce * w * adaptive * mm;
            msum += mm;
        }
    }

    // wave (64-lane) butterfly reduction
    #pragma unroll
    for (int off = 32; off > 0; off >>= 1) {
        lsum += __shfl_xor(lsum, off);
        msum += __shfl_xor(msum, off);
    }

    __shared__ float sL[BLOCK / 64];
    __shared__ float sM[BLOCK / 64];
    const int wave = threadIdx.x >> 6;
    const int lane = threadIdx.x & 63;
    if (lane == 0) { sL[wave] = lsum; sM[wave] = msum; }
    __syncthreads();

    if (threadIdx.x == 0) {
        float bl = 0.0f, bm = 0.0f;
        #pragma unroll
        for (int i = 0; i < BLOCK / 64; ++i) { bl += sL[i]; bm += sM[i]; }
        atomicAdd(&sums[0], bl);
        atomicAdd(&sums[1], bm);
    }
}

__global__ void bfl_finalize(const float* __restrict__ sums, float* __restrict__ out)
{
    const float ls = sums[0];
    const float ms = sums[1];
    out[0] = (ms > 0.0f) ? (ls / ms) : 0.0f;
}

extern "C" void kernel_launch(void* const* d_in, const int* in_sizes, int n_in,
                              void* d_out, int out_size, void* d_ws, size_t ws_size,
                              hipStream_t stream) {
    const float* inputs  = (const float*)d_in[0];
    const int*   targets = (const int*)d_in[1];
    const float* mask    = (const float*)d_in[2];
    float*       out     = (float*)d_out;
    float*       sums    = (float*)d_ws;

    hipMemsetAsync(sums, 0, 2 * sizeof(float), stream);

    dim3 grid(BLOCKS_PER_ROW, B_DIM);
    bfl_main<<<grid, BLOCK, 0, stream>>>(inputs, targets, mask, sums);
    bfl_finalize<<<1, 1, 0, stream>>>(sums, out);
}

// Round 2
// 290.203 us; speedup vs baseline: 2.8646x; 2.8646x over previous
//
#include <hip/hip_runtime.h>
#include <math.h>

// BoundaryFocalLoss: B=128, T=200000, f32 inputs, i32 targets, f32 mask -> scalar f32.
// Memory-bound: 12 B/elem * 25.6M = ~307 MB read. Roofline @6.3 TB/s ~= 49 us.
//
// R1 post-mortem: 654 us was same-address atomicAdd serialization (50k atomics
// from 25k blocks to 2 words ~= 30 cyc each ~= 630 us). Fix: 1024 blocks,
// grid-stride loop, per-block partials to d_ws (no atomics), 2nd kernel reduces.

#define B_DIM 128
#define T_DIM 200000

constexpr int GROUPS_PER_ROW  = T_DIM / 4;   // 50000 float4-groups per row
constexpr int BLOCK           = 256;
constexpr int BLOCKS_X        = 8;           // blocks per row
constexpr int ROW_STRIDE      = BLOCKS_X * BLOCK;                       // 2048 groups/iter
constexpr int NUM_ITERS       = (GROUPS_PER_ROW + ROW_STRIDE - 1) / ROW_STRIDE;  // 25
constexpr int NUM_PARTIALS    = BLOCKS_X * B_DIM;                       // 1024

__global__ __launch_bounds__(BLOCK) void bfl_main(
    const float* __restrict__ inputs,
    const int*   __restrict__ targets,
    const float* __restrict__ mask,
    float2*      __restrict__ partials)   // [NUM_PARTIALS] = (loss_sum, mask_sum)
{
    const int b = blockIdx.y;
    const long long row = (long long)b * T_DIM;
    const float4* __restrict__ inp4 = (const float4*)(inputs + row);
    const float4* __restrict__ msk4 = (const float4*)(mask + row);
    const int4*   __restrict__ tgt4 = (const int4*)(targets + row);

    float lsum = 0.0f, msum = 0.0f;

    for (int iter = 0; iter < NUM_ITERS; ++iter) {
        const int g_row = iter * ROW_STRIDE + blockIdx.x * BLOCK + threadIdx.x;
        if (g_row >= GROUPS_PER_ROW) break;

        const int t0 = g_row * 4;

        const float4 x4   = inp4[g_row];
        const float4 m4   = msk4[g_row];
        const int4   curr = tgt4[g_row];
        const int4   prev = (g_row > 0)
            ? tgt4[g_row - 1] : make_int4(curr.x, curr.x, curr.x, curr.x);
        const int4   next = (g_row < GROUPS_PER_ROW - 1)
            ? tgt4[g_row + 1] : make_int4(curr.w, curr.w, curr.w, curr.w);

        // tg[k] = targets[t0 - 4 + k], k = 0..10  (halo -4..+6)
        const int tg[11] = {prev.x, prev.y, prev.z, prev.w,
                            curr.x, curr.y, curr.z, curr.w,
                            next.x, next.y, next.z};

        // trans bit k <-> j = t0 - 4 + k; trans[j] valid for 1 <= j <= T-1
        unsigned mbits = 0u;
        #pragma unroll
        for (int k = 1; k <= 10; ++k) {
            const int j = t0 - 4 + k;
            const bool valid = (j >= 1) && (j < T_DIM);
            if (valid && (tg[k] != tg[k - 1])) mbits |= (1u << k);
        }

        const float xs[4] = {x4.x, x4.y, x4.z, x4.w};
        const float ms[4] = {m4.x, m4.y, m4.z, m4.w};
        const int   ts[4] = {curr.x, curr.y, curr.z, curr.w};

        #pragma unroll
        for (int ii = 0; ii < 4; ++ii) {
            const float x  = xs[ii];
            const float mm = ms[ii];
            const bool pos = ((float)ts[ii]) > 0.5f;

            const float smoothed = pos ? 0.975f : 0.025f;   // pos*(1-ls) + ls/2
            // boundary[i] = OR of trans bits (ii+1 .. ii+7)  <-> j in [i-3, i+3]
            const float w = ((mbits >> (ii + 1)) & 0x7Fu) ? 5.0f : 1.0f;

            // ea = exp(-|x|); shared by softplus and |p - 0.5| identity:
            // |sigmoid(x) - 0.5| = |1 - ea| / (2*(1 + ea))   (same for +/- x)
            const float ea = __expf(-fabsf(x));
            const float opea = 1.0f + ea;
            const float r = 1.0f / opea;                     // rcp + NR, few ops
            const float adaptive = 1.0f - 0.5f * fabsf(1.0f - ea) * r;

            const float bce = fmaxf(x, 0.0f) - x * smoothed + __logf(opea);
            const float pt  = __expf(-bce);
            const float alpha_w = pos ? 0.25f : 0.75f;
            const float om = 1.0f - pt;

            lsum += alpha_w * om * om * bce * w * adaptive * mm;
            msum += mm;
        }
    }

    // wave (64-lane) butterfly reduction
    #pragma unroll
    for (int off = 32; off > 0; off >>= 1) {
        lsum += __shfl_xor(lsum, off);
        msum += __shfl_xor(msum, off);
    }

    __shared__ float sL[BLOCK / 64];
    __shared__ float sM[BLOCK / 64];
    const int wave = threadIdx.x >> 6;
    const int lane = threadIdx.x & 63;
    if (lane == 0) { sL[wave] = lsum; sM[wave] = msum; }
    __syncthreads();

    if (threadIdx.x == 0) {
        float bl = 0.0f, bm = 0.0f;
        #pragma unroll
        for (int i = 0; i < BLOCK / 64; ++i) { bl += sL[i]; bm += sM[i]; }
        partials[blockIdx.y * BLOCKS_X + blockIdx.x] = make_float2(bl, bm);
    }
}

__global__ __launch_bounds__(BLOCK) void bfl_reduce(
    const float2* __restrict__ partials,
    float*        __restrict__ out)
{
    float ls = 0.0f, ms = 0.0f;
    #pragma unroll
    for (int i = 0; i < NUM_PARTIALS / BLOCK; ++i) {
        const float2 p = partials[i * BLOCK + threadIdx.x];
        ls += p.x; ms += p.y;
    }

    #pragma unroll
    for (int off = 32; off > 0; off >>= 1) {
        ls += __shfl_xor(ls, off);
        ms += __shfl_xor(ms, off);
    }

    __shared__ float sL[BLOCK / 64];
    __shared__ float sM[BLOCK / 64];
    const int wave = threadIdx.x >> 6;
    const int lane = threadIdx.x & 63;
    if (lane == 0) { sL[wave] = ls; sM[wave] = ms; }
    __syncthreads();

    if (threadIdx.x == 0) {
        float bl = 0.0f, bm = 0.0f;
        #pragma unroll
        for (int i = 0; i < BLOCK / 64; ++i) { bl += sL[i]; bm += sM[i]; }
        out[0] = (bm > 0.0f) ? (bl / bm) : 0.0f;
    }
}

extern "C" void kernel_launch(void* const* d_in, const int* in_sizes, int n_in,
                              void* d_out, int out_size, void* d_ws, size_t ws_size,
                              hipStream_t stream) {
    const float* inputs  = (const float*)d_in[0];
    const int*   targets = (const int*)d_in[1];
    const float* mask    = (const float*)d_in[2];
    float*       out     = (float*)d_out;
    float2*      partials = (float2*)d_ws;

    dim3 grid(BLOCKS_X, B_DIM);
    bfl_main<<<grid, BLOCK, 0, stream>>>(inputs, targets, mask, partials);
    bfl_reduce<<<1, BLOCK, 0, stream>>>(partials, out);
}